// Round 10
// baseline (610.446 us; speedup 1.0000x reference)
//
#include <hip/hip_runtime.h>
#include <hip/hip_bf16.h>

typedef __hip_bfloat16 bf16;
typedef __attribute__((ext_vector_type(8))) short short8;
typedef __attribute__((ext_vector_type(4))) float floatx4;

#define NC 4
#define BB 2
#define TS 16
#define CHN 3
#define HH 256
#define WW 256
#define KQ 256
#define EE 256
#define BKT 512          // B*K
#define HW 65536         // H*W
#define IMG_CHUNK 1024   // images per patch-pipeline chunk (2 chunks of 2048)
#define NSEG 33
#define CH1 32
#define CH1P 40
#define CH2 64
#define CH2P 72
#define PW 11            // plane width (11 cols)

__device__ __forceinline__ float tof(bf16 x){ return __bfloat162float(x); }
__device__ __forceinline__ bf16 tobf(float x){ return __float2bfloat16(x); }
// exact GELU (erf form) — R9's tanh approximation exceeded the absmax budget
__device__ __forceinline__ float gelu_f(float x){ return 0.5f*x*(1.f+erff(x*0.70710678118654752f)); }
__device__ __forceinline__ float ldx(const void* p, size_t i, int bf){
    return bf ? tof(((const bf16*)p)[i]) : ((const float*)p)[i];
}

struct CvtArgs { const void* src[NSEG]; int dstoff[NSEG]; int cnt[NSEG]; };

// ---------------------------------------------------------------- dtype detect
__global__ void detect_kernel(const void* camF, int* flag){
    unsigned short w0 = ((const unsigned short*)camF)[0];
    *flag = (w0 != 0) ? 1 : 0;
}

// ---------------------------------------------------------------- merged prep (race-free: all segs read d_in directly)
__global__ __launch_bounds__(256) void prep_kernel(
    CvtArgs a, float* pool, const void* m1w, bf16* m1w_bf,
    const void* c2w_raw, const void* c3w_raw, bf16* w2cl, bf16* w3cl,
    const void* linv_raw, const void* f1w_raw, const void* f2w_raw, const void* m2w_raw,
    bf16* linv_bf, bf16* f1w_bf, bf16* f2w_bf, bf16* m2w_bf,
    float* zbuf, int znum, const int* flagp)
{
    int bf = *flagp;
    int seg = blockIdx.y;
    int i0 = blockIdx.x*256 + threadIdx.x;
    int stride = gridDim.x*256;
    if (seg < NSEG){
        const void* s = a.src[seg];
        float* d = pool + a.dstoff[seg];
        int n = a.cnt[seg];
        for (int i=i0; i<n; i+=stride)
            d[i] = bf ? tof(((const bf16*)s)[i]) : ((const float*)s)[i];
    } else if (seg == NSEG){
        int n = 512*10368;
        if (bf){ const bf16* s=(const bf16*)m1w; for (int i=i0;i<n;i+=stride) m1w_bf[i]=s[i]; }
        else   { const float* s=(const float*)m1w; for (int i=i0;i<n;i+=stride) m1w_bf[i]=tobf(s[i]); }
    } else if (seg == NSEG+1){
        for (int i=i0; i<128*64*9; i+=stride){
            if (i < 64*32*9){
                int oc = i/(32*9), r = i%(32*9); int ic = r/9, tap = r%9;
                w2cl[tap*(64*CH1) + oc*CH1 + ic] = tobf(ldx(c2w_raw, i, bf));
            }
            int oc = i/(64*9), r = i%(64*9); int ic = r/9, tap = r%9;
            w3cl[tap*(128*CH2) + oc*CH2 + ic] = tobf(ldx(c3w_raw, i, bf));
        }
    } else if (seg == NSEG+2){
        for (int i=i0; i<256*1024; i+=stride){
            int r=i>>10, c=i&1023;
            linv_bf[i] = tobf(c<1000 ? ldx(linv_raw, (size_t)r*1000+c, bf) : 0.f);
            f1w_bf[i]  = tobf(ldx(f1w_raw, i, bf));
            f2w_bf[i]  = tobf(ldx(f2w_raw, i, bf));
            if (i < 256*512) m2w_bf[i] = tobf(ldx(m2w_raw, i, bf));
        }
    } else {
        for (int i=i0; i<znum; i+=stride) zbuf[i] = 0.f;
    }
}

// ---------------------------------------------------------------- final output: obuf + bias -> d_out (dual dtype)
__global__ __launch_bounds__(256) void fin_out_kernel(const float* __restrict__ obuf,
                                                      const float* __restrict__ bias,
                                                      void* __restrict__ out, const int* __restrict__ flagp,
                                                      int total, int mask){
    int bf = *flagp;
    for (int i = blockIdx.x*256 + threadIdx.x; i < total; i += gridDim.x*256){
        float v = obuf[i] + bias[i & mask];
        if (bf) ((bf16*)out)[i] = tobf(v);
        else    ((float*)out)[i] = v;
    }
}

// ---------------------------------------------------------------- projection
__global__ __launch_bounds__(256) void proj_kernel(
    const float* __restrict__ qc, const float* __restrict__ camR,
    const float* __restrict__ camC, const float* __restrict__ camF,
    const float* __restrict__ camP,
    float* __restrict__ p2d, float* __restrict__ visf,
    void* __restrict__ dout, const int* __restrict__ flagp)
{
    int idx = blockIdx.x*256 + threadIdx.x;
    if (idx >= NC*BKT) return;
    int bf = *flagp;
    int c = idx / BKT, bk = idx % BKT;
    float dx = qc[bk*3+0] - camC[c*3+0];
    float dy = qc[bk*3+1] - camC[c*3+1];
    float dz = qc[bk*3+2] - camC[c*3+2];
    float X0 = camR[c*9+0]*dx + camR[c*9+1]*dy + camR[c*9+2]*dz;
    float X1 = camR[c*9+3]*dx + camR[c*9+4]*dy + camR[c*9+5]*dz;
    float X2 = camR[c*9+6]*dx + camR[c*9+7]*dy + camR[c*9+8]*dz;
    float z = fmaxf(X2, 1e-6f);
    float u = X0/z*camF[c*2+0] + camP[c*2+0];
    float v = X1/z*camF[c*2+1] + camP[c*2+1];
    p2d[idx*2+0] = u; p2d[idx*2+1] = v;
    bool vis = (X2 > 0.f) && (u >= 2.f) && (u <= (float)WW-2.f) && (v >= 2.f) && (v <= (float)HH-2.f);
    visf[idx] = vis ? 1.f : 0.f;
    float vv = vis ? 1.f : 0.f;
    size_t vidx = (size_t)BB*KQ*NC*EE + (size_t)bk*NC + c;
    if (bf) ((bf16*)dout)[vidx] = tobf(vv);
    else    ((float*)dout)[vidx] = vv;
}

// ---------------------------------------------------------------- cube sampling
__global__ __launch_bounds__(128) void cube_kernel(
    const void* __restrict__ views, const float* __restrict__ qc,
    const int* __restrict__ qtime,
    const float* __restrict__ camR, const float* __restrict__ camC,
    const float* __restrict__ camF, const float* __restrict__ camP,
    const float* __restrict__ csc, float* __restrict__ mv,
    const int* __restrict__ flagp)
{
    int bk = blockIdx.x; int p = threadIdx.x;
    if (p >= 125) return;
    int bf = *flagp;
    int b = bk / KQ;
    float cs2 = csc[0] * 2.f;
    int i = p/25, j = (p/5)%5, kz = p%5;
    float qx = qc[bk*3+0] + (float)(i-2)*cs2;
    float qy = qc[bk*3+1] + (float)(j-2)*cs2;
    float qz = qc[bk*3+2] + (float)(kz-2)*cs2;
    int t = qtime[bk];
    float a0=0.f,a1=0.f,a2=0.f,msum=0.f;
    for (int c=0;c<NC;++c){
        float dx=qx-camC[c*3+0], dy=qy-camC[c*3+1], dz=qz-camC[c*3+2];
        float X0 = camR[c*9+0]*dx+camR[c*9+1]*dy+camR[c*9+2]*dz;
        float X1 = camR[c*9+3]*dx+camR[c*9+4]*dy+camR[c*9+5]*dz;
        float X2 = camR[c*9+6]*dx+camR[c*9+7]*dy+camR[c*9+8]*dz;
        float z = fmaxf(X2,1e-6f);
        float u = X0/z*camF[c*2+0]+camP[c*2+0];
        float v = X1/z*camF[c*2+1]+camP[c*2+1];
        if (u>=0.f && u<=(float)WW && v>=0.f && v<=(float)HH){
            msum += 1.f;
            float x = u-0.5f, y = v-0.5f;
            float xf = floorf(x), yf = floorf(y);
            int ix=(int)xf, iy=(int)yf;
            float wx=x-xf, wy=y-yf;
            size_t base = (size_t)((c*BB+b)*TS + t)*CHN*HW;
            float wxs[2]={1.f-wx,wx}, wys[2]={1.f-wy,wy};
            #pragma unroll
            for (int ty=0;ty<2;++ty){
                int yy=iy+ty; if (yy<0||yy>=HH) continue;
                #pragma unroll
                for (int tx=0;tx<2;++tx){
                    int xx=ix+tx; if (xx<0||xx>=WW) continue;
                    float wt=wys[ty]*wxs[tx];
                    size_t o = base + (size_t)yy*WW+xx;
                    a0 += wt*ldx(views,o,bf);
                    a1 += wt*ldx(views,o+HW,bf);
                    a2 += wt*ldx(views,o+2*HW,bf);
                }
            }
        }
    }
    float cnt = fmaxf(msum,1.f);
    mv[(bk*125+p)*3+0]=a0/cnt;
    mv[(bk*125+p)*3+1]=a1/cnt;
    mv[(bk*125+p)*3+2]=a2/cnt;
}

// ---------------------------------------------------------------- 3D conv (v2v) + gelu -> bf16, padded K=1024 rows
__global__ __launch_bounds__(128) void vol_conv3d_kernel(
    const float* __restrict__ mv, const float* __restrict__ w,
    const float* __restrict__ bias, bf16* __restrict__ outb)
{
    int bk = blockIdx.x; int tid = threadIdx.x;
    __shared__ float vol[3][7][7][7];
    __shared__ float ws[648];
    __shared__ float bs[8];
    for (int idx=tid; idx<3*343; idx+=128) ((float*)vol)[idx]=0.f;
    for (int idx=tid; idx<648; idx+=128) ws[idx]=w[idx];
    if (tid<8) bs[tid]=bias[tid];
    __syncthreads();
    if (tid<125){
        int i=tid/25, j=(tid/5)%5, kz=tid%5;
        #pragma unroll
        for (int ch=0;ch<3;++ch) vol[ch][kz+1][j+1][i+1] = mv[(bk*125+tid)*3+ch];
    }
    __syncthreads();
    if (tid >= 104 && tid < 128) outb[bk*1024 + 1000 + (tid-104)] = tobf(0.f);
    if (tid<125){
        int w2=tid/25, h2=(tid/5)%5, d2=tid%5;
        for (int oc=0;oc<8;++oc){
            float acc = bs[oc];
            #pragma unroll
            for (int ic=0;ic<3;++ic)
              #pragma unroll
              for (int dz=0;dz<3;++dz)
                #pragma unroll
                for (int dy=0;dy<3;++dy)
                  #pragma unroll
                  for (int dxx=0;dxx<3;++dxx)
                    acc += vol[ic][d2+dz][h2+dy][w2+dxx] * ws[(((oc*3+ic)*3+dz)*3+dy)*3+dxx];
            outb[bk*1024 + oc*125 + tid] = tobf(gelu_f(acc));
        }
    }
}

// ---------------------------------------------------------------- fused patch sample + conv1 (VALU) + conv2/conv3 (MFMA)
// LDS: a2cl 17424 + a1cl 9680 + w1s 3456 + patch 1452 = 32,012 B -> 5 blocks/CU
__global__ __launch_bounds__(256) void patchconv_mfma_kernel(
    const void* __restrict__ views, const float* __restrict__ p2d,
    const int* __restrict__ qtime,
    const float* __restrict__ w1, const float* __restrict__ b1,
    const bf16* __restrict__ w2cl, const float* __restrict__ b2,
    const bf16* __restrict__ w3cl, const float* __restrict__ b3,
    bf16* __restrict__ act_out, int img0, const int* __restrict__ flagp)
{
    int img = img0 + blockIdx.x;
    int c = img>>9, b = (img>>8)&1, k = img&255;
    int bk = b*KQ + k;
    int tid = threadIdx.x;
    int wave = tid>>6, lane = tid&63;

    __shared__ __align__(16) bf16 a2cl[11*PW*CH2P];   // 17,424 B
    __shared__ __align__(16) bf16 a1cl[11*PW*CH1P];   // 9,680 B
    __shared__ float w1s[864];                        // 3,456 B
    __shared__ float patch[3][11][11];                // 1,452 B

    for (int i=tid;i<3*11*11;i+=256) ((float*)patch)[i]=0.f;
    for (int i=tid;i<864;i+=256) w1s[i]=w1[i];
    {
        unsigned int* z1=(unsigned int*)a1cl; int n1 = 11*PW*CH1P/2;
        for (int i=tid;i<n1;i+=256) z1[i]=0u;
        unsigned int* z2=(unsigned int*)a2cl; int n2 = 11*PW*CH2P/2;
        for (int i=tid;i<n2;i+=256) z2[i]=0u;
    }
    __syncthreads();
    if (tid<81){
        int bf = *flagp;
        float u=p2d[(c*BKT+bk)*2+0], v=p2d[(c*BKT+bk)*2+1];
        int t=qtime[bk];
        int r=tid/9,q=tid%9;
        float x=u+(float)(q-4), y=v+(float)(r-4);
        float xf=floorf(x), yf=floorf(y);
        int ix=(int)xf, iy=(int)yf;
        float wx=x-xf, wy=y-yf;
        size_t base = (size_t)((c*BB+b)*TS+t)*CHN*HW;
        float v0=0.f,v1=0.f,v2=0.f;
        float wxs[2]={1.f-wx,wx}, wys[2]={1.f-wy,wy};
        #pragma unroll
        for (int ty=0;ty<2;++ty){
            int yy=iy+ty; if (yy<0||yy>=HH) continue;
            #pragma unroll
            for (int tx=0;tx<2;++tx){
                int xx=ix+tx; if (xx<0||xx>=WW) continue;
                float wt=wys[ty]*wxs[tx];
                size_t o = base + (size_t)yy*WW+xx;
                v0 += wt*ldx(views,o,bf);
                v1 += wt*ldx(views,o+HW,bf);
                v2 += wt*ldx(views,o+2*HW,bf);
            }
        }
        patch[0][r+1][q+1]=v0; patch[1][r+1][q+1]=v1; patch[2][r+1][q+1]=v2;
    }
    __syncthreads();
    for (int o=tid;o<81*32;o+=256){
        int oc=o&31, pp=o>>5;
        int r=pp/9, q=pp-9*r;
        float acc=b1[oc];
        #pragma unroll
        for (int ic=0;ic<3;++ic)
          #pragma unroll
          for (int dy2=0;dy2<3;++dy2)
            #pragma unroll
            for (int dx2=0;dx2<3;++dx2)
              acc += patch[ic][r+dy2][q+dx2]*w1s[((oc*3+ic)*3+dy2)*3+dx2];
        a1cl[((r+1)*PW+(q+1))*CH1P + oc] = tobf(gelu_f(acc));
    }
    __syncthreads();
    int mrow = lane&15;
    int kgrp = lane>>4;
    int koff = kgrp<<3;
    {
        int baseoff[6];
        #pragma unroll
        for (int m=0;m<6;++m){
            int pos = m*16 + mrow; if (pos>80) pos=80;
            int r=pos/9, q=pos-9*r;
            baseoff[m] = (r*PW+q)*CH1P + koff;
        }
        floatx4 acc2[6];
        #pragma unroll
        for (int m=0;m<6;++m) acc2[m]=(floatx4){0.f,0.f,0.f,0.f};
        int n0 = wave<<4;
        #pragma unroll
        for (int tap=0; tap<9; ++tap){
            int dy=tap/3, dx=tap-3*dy;
            short8 bfrag = *(const short8*)(w2cl + ((size_t)tap*64 + n0 + mrow)*CH1 + koff);
            int toff = (dy*PW+dx)*CH1P;
            #pragma unroll
            for (int m=0;m<6;++m){
                short8 afrag = *(const short8*)&a1cl[baseoff[m]+toff];
                acc2[m] = __builtin_amdgcn_mfma_f32_16x16x32_bf16(afrag, bfrag, acc2[m], 0,0,0);
            }
        }
        int oc = n0 + mrow;
        float bb = b2[oc];
        #pragma unroll
        for (int m=0;m<6;++m){
            #pragma unroll
            for (int rg=0;rg<4;++rg){
                int pos = m*16 + (kgrp<<2)+rg;
                if (pos<=80){
                    int r=pos/9,q=pos-9*r;
                    a2cl[((r+1)*PW+(q+1))*CH2P + oc] = tobf(gelu_f(acc2[m][rg]+bb));
                }
            }
        }
    }
    __syncthreads();
    {
        int baseoff[6];
        #pragma unroll
        for (int m=0;m<6;++m){
            int pos = m*16 + mrow; if (pos>80) pos=80;
            int r=pos/9, q=pos-9*r;
            baseoff[m] = (r*PW+q)*CH2P;
        }
        floatx4 acc3[2][6];
        #pragma unroll
        for (int nt=0;nt<2;++nt)
          #pragma unroll
          for (int m=0;m<6;++m) acc3[nt][m]=(floatx4){0.f,0.f,0.f,0.f};
        int n0 = wave<<5;
        #pragma unroll
        for (int tap=0; tap<9; ++tap){
            int dy=tap/3, dx=tap-3*dy;
            int toff = (dy*PW+dx)*CH2P;
            #pragma unroll
            for (int ks=0;ks<2;++ks){
                int kof2 = (ks<<5) + koff;
                short8 b0 = *(const short8*)(w3cl + ((size_t)tap*128 + n0      + mrow)*CH2 + kof2);
                short8 b1f= *(const short8*)(w3cl + ((size_t)tap*128 + n0 + 16 + mrow)*CH2 + kof2);
                #pragma unroll
                for (int m=0;m<6;++m){
                    short8 af = *(const short8*)&a2cl[baseoff[m]+toff+kof2];
                    acc3[0][m] = __builtin_amdgcn_mfma_f32_16x16x32_bf16(af, b0,  acc3[0][m], 0,0,0);
                    acc3[1][m] = __builtin_amdgcn_mfma_f32_16x16x32_bf16(af, b1f, acc3[1][m], 0,0,0);
                }
            }
        }
        #pragma unroll
        for (int nt=0;nt<2;++nt){
            int oc = n0 + (nt<<4) + mrow;
            float bb = b3[oc];
            #pragma unroll
            for (int m=0;m<6;++m){
                #pragma unroll
                for (int rg=0;rg<4;++rg){
                    int pos = m*16 + (kgrp<<2)+rg;
                    if (pos<=80)
                        act_out[(size_t)blockIdx.x*10368 + oc*81 + pos] = tobf(gelu_f(acc3[nt][m][rg]+bb));
                }
            }
        }
    }
}

// ---------------------------------------------------------------- generic MFMA bf16 GEMM, double-buffered LDS + reg prefetch
template<int OUT>
__global__ __launch_bounds__(256) void gemm_bf16_kernel(
    const bf16* __restrict__ A, const bf16* __restrict__ W, const float* __restrict__ bias,
    float* __restrict__ Cf, bf16* __restrict__ Cb, int M, int N, int K, int iters)
{
    __shared__ bf16 As[2][64][72];
    __shared__ bf16 Bs[2][64][72];
    int tid = threadIdx.x;
    int wave = tid>>6, lane = tid&63;
    int m0 = blockIdx.y<<6, n0 = blockIdx.x<<6;
    int kt0 = blockIdx.z*iters;
    int lr = tid>>3;
    int lc = (tid&7)<<3;
    const bf16* Ap0 = A + (size_t)(m0+lr)*K    + (kt0<<6) + lc;
    const bf16* Ap1 = A + (size_t)(m0+lr+32)*K + (kt0<<6) + lc;
    const bf16* Wp0 = W + (size_t)(n0+lr)*K    + (kt0<<6) + lc;
    const bf16* Wp1 = W + (size_t)(n0+lr+32)*K + (kt0<<6) + lc;
    uint4 ra0 = *(const uint4*)Ap0;
    uint4 ra1 = *(const uint4*)Ap1;
    uint4 rb0 = *(const uint4*)Wp0;
    uint4 rb1 = *(const uint4*)Wp1;
    floatx4 acc[4];
    #pragma unroll
    for (int j=0;j<4;++j) acc[j] = (floatx4){0.f,0.f,0.f,0.f};
    int arow = (wave<<4) + (lane&15);
    int koff = (lane>>4)<<3;
    int nrow = lane&15;
    *(uint4*)&As[0][lr][lc]    = ra0;
    *(uint4*)&As[0][lr+32][lc] = ra1;
    *(uint4*)&Bs[0][lr][lc]    = rb0;
    *(uint4*)&Bs[0][lr+32][lc] = rb1;
    __syncthreads();
    for (int it=0; it<iters; ++it){
        int cur = it&1;
        if (it+1<iters){
            int off = (it+1)<<6;
            ra0 = *(const uint4*)(Ap0+off);
            ra1 = *(const uint4*)(Ap1+off);
            rb0 = *(const uint4*)(Wp0+off);
            rb1 = *(const uint4*)(Wp1+off);
        }
        #pragma unroll
        for (int kk=0; kk<64; kk+=32){
            short8 af = *(const short8*)&As[cur][arow][kk+koff];
            #pragma unroll
            for (int j=0;j<4;++j){
                short8 bfr = *(const short8*)&Bs[cur][(j<<4)+nrow][kk+koff];
                acc[j] = __builtin_amdgcn_mfma_f32_16x16x32_bf16(af, bfr, acc[j], 0, 0, 0);
            }
        }
        if (it+1<iters){
            __syncthreads();
            int nxt = cur^1;
            *(uint4*)&As[nxt][lr][lc]    = ra0;
            *(uint4*)&As[nxt][lr+32][lc] = ra1;
            *(uint4*)&Bs[nxt][lr][lc]    = rb0;
            *(uint4*)&Bs[nxt][lr+32][lc] = rb1;
            __syncthreads();
        }
    }
    int crow = (wave<<4) + ((lane>>4)<<2);
    int ccol = lane&15;
    #pragma unroll
    for (int j=0;j<4;++j){
        int n = n0 + (j<<4) + ccol;
        if (OUT==0){
            #pragma unroll
            for (int r=0;r<4;++r)
                atomicAdd(&Cf[(size_t)(m0+crow+r)*N + n], acc[j][r]);
        } else {
            float bb = bias[n];
            #pragma unroll
            for (int r=0;r<4;++r)
                Cb[(size_t)(m0+crow+r)*N + n] = tobf(gelu_f(acc[j][r] + bb));
        }
    }
}

// ---------------------------------------------------------------- mlp1 finalize: bf16 out = gelu(acc + bias)
__global__ __launch_bounds__(256) void mlp1_fin_kernel(const float* __restrict__ C,
                                                       const float* __restrict__ bias,
                                                       bf16* __restrict__ Cb, int total, int Nmask){
    for (int i = blockIdx.x*256 + threadIdx.x; i < total; i += gridDim.x*256)
        Cb[i] = tobf(gelu_f(C[i] + bias[i & Nmask]));
}

// ---------------------------------------------------------------- terms + gates + fuse -> bf16 (evol/embp bias folded in)
__global__ __launch_bounds__(256) void terms_kernel(
    const float* __restrict__ p2d, const float* __restrict__ visf,
    const float* __restrict__ evol, const float* __restrict__ linv_b,
    const float* __restrict__ embp, const float* __restrict__ m2_b,
    const float* __restrict__ lin_pos_w, const float* __restrict__ lin_pos_b,
    const float* __restrict__ lin_depth_w, const float* __restrict__ lin_depth_b,
    const float* __restrict__ tq_emb, const float* __restrict__ tt_emb,
    const float* __restrict__ vis_tab,
    const float* __restrict__ gate_w, const float* __restrict__ gate_b,
    const int* __restrict__ qtime, const int* __restrict__ ttime,
    const float* __restrict__ qc, const float* __restrict__ camC,
    const float* __restrict__ csc, const float* __restrict__ dns,
    bf16* __restrict__ fused)
{
    int row = blockIdx.x;
    int c = row & 3; int bk = row >> 2;
    int tid = threadIdx.x;
    __shared__ float feats[40];
    __shared__ float dfeat[20];
    __shared__ float terms[7][256];
    __shared__ float wred[4][7];
    __shared__ float gates_s[7];
    float u = p2d[(c*BKT+bk)*2+0], v = p2d[(c*BKT+bk)*2+1];
    if (tid < 40){
        int j = tid/20; int rem = tid%20;
        float xval = (j==0) ? u*(1.f/(float)WW) : v*(1.f/(float)HH);
        int fi = rem % 10; bool iscos = (rem >= 10);
        float arg = xval * (float)(1<<fi) * 3.14159265358979323846f;
        feats[tid] = iscos ? cosf(arg) : sinf(arg);
    } else if (tid < 60){
        int rem = tid-40;
        float dx = qc[bk*3+0]-camC[c*3+0];
        float dy = qc[bk*3+1]-camC[c*3+1];
        float dz = qc[bk*3+2]-camC[c*3+2];
        float dep = sqrtf(dx*dx+dy*dy+dz*dz) / (csc[0] * dns[0]);
        int fi = rem % 10; bool iscos = (rem >= 10);
        float arg = dep * (float)(1<<fi) * 3.14159265358979323846f;
        dfeat[rem] = iscos ? cosf(arg) : sinf(arg);
    }
    __syncthreads();
    int e = tid;
    float pos = lin_pos_b[e];
    for (int j2=0;j2<40;++j2) pos += feats[j2]*lin_pos_w[e*40+j2];
    float dep = lin_depth_b[e];
    for (int j2=0;j2<20;++j2) dep += dfeat[j2]*lin_depth_w[e*20+j2];
    float vol = evol[bk*256+e] + linv_b[e];
    int img = (c*BB + (bk>>8))*KQ + (bk&255);
    float pat = embp[(size_t)img*256+e] + m2_b[e];
    int tq = qtime[bk], tt2 = ttime[bk];
    float qtv = tq_emb[tq*256+e];
    float ttv = tt_emb[tt2*256+e];
    int vb = (visf[c*BKT+bk] > 0.5f) ? 1 : 0;
    float viv = vis_tab[vb*256+e];
    terms[0][e]=pos; terms[1][e]=vol; terms[2][e]=pat; terms[3][e]=qtv;
    terms[4][e]=ttv; terms[5][e]=viv; terms[6][e]=dep;
    __syncthreads();
    float pg[7];
    #pragma unroll
    for (int g=0;g<7;++g) pg[g]=0.f;
    for (int j2=tid; j2<1792; j2+=256){
        float cv = ((const float*)terms)[j2];
        #pragma unroll
        for (int g=0;g<7;++g) pg[g] += cv * gate_w[g*1792 + j2];
    }
    #pragma unroll
    for (int g=0;g<7;++g){
        #pragma unroll
        for (int off=32; off>0; off>>=1) pg[g] += __shfl_down(pg[g], off, 64);
    }
    int wave = tid >> 6, lane = tid & 63;
    if (lane==0){
        #pragma unroll
        for (int g=0;g<7;++g) wred[wave][g]=pg[g];
    }
    __syncthreads();
    if (tid < 7){
        float s = wred[0][tid]+wred[1][tid]+wred[2][tid]+wred[3][tid] + gate_b[tid];
        gates_s[tid] = 1.f/(1.f+expf(-s));
    }
    __syncthreads();
    float fv = 0.f;
    #pragma unroll
    for (int g=0;g<7;++g) fv += gates_s[g]*terms[g][e];
    fused[(size_t)row*256 + e] = tobf(fv);
}

// ---------------------------------------------------------------- launch
extern "C" void kernel_launch(void* const* d_in, const int* in_sizes, int n_in,
                              void* d_out, int out_size, void* d_ws, size_t ws_size,
                              hipStream_t stream) {
    const void* views  = d_in[0];
    const int*  qtime  = (const int*)d_in[6];
    const int*  ttime  = (const int*)d_in[7];
    const void* m1w    = d_in[23];

    char* base = (char*)d_ws;
    int*   flag = (int*)base;                       // 256 B
    float* pool = (float*)(base + 256);

    CvtArgs ca; int poff = 0; int ns = 0;
    auto add = [&](const void* p, int n)->float* {
        ca.src[ns]=p; ca.dstoff[ns]=poff; ca.cnt[ns]=n;
        float* r = pool+poff; poff += n; ns++; return r;
    };
    float* P_camR = add(d_in[1],36);
    float* P_camC = add(d_in[2],12);
    float* P_camF = add(d_in[3],8);
    float* P_camP = add(d_in[4],8);
    float* P_qc   = add(d_in[5],1536);
    float* P_csc  = add(d_in[8],1);
    float* P_dns  = add(d_in[30],1);
    float* P_v2vw = add(d_in[9],648);
    float* P_v2vb = add(d_in[10],8);
    float* P_linvw= add(d_in[11],256000);
    float* P_linvb= add(d_in[12],256);
    float* P_linpw= add(d_in[13],10240);
    float* P_linpb= add(d_in[14],256);
    float* P_lindw= add(d_in[15],5120);
    float* P_lindb= add(d_in[16],256);
    float* P_c1w  = add(d_in[17],864);
    float* P_c1b  = add(d_in[18],32);
    float* P_c2w  = add(d_in[19],18432);
    float* P_c2b  = add(d_in[20],64);
    float* P_c3w  = add(d_in[21],73728);
    float* P_c3b  = add(d_in[22],128);
    float* P_m1b  = add(d_in[24],512);
    float* P_m2w  = add(d_in[25],131072);
    float* P_m2b  = add(d_in[26],256);
    float* P_tq   = add(d_in[27],4096);
    float* P_tt   = add(d_in[28],4096);
    float* P_vtab = add(d_in[29],512);
    float* P_gw   = add(d_in[31],12544);
    float* P_gb   = add(d_in[32],7);
    float* P_f1w  = add(d_in[33],262144);
    float* P_f1b  = add(d_in[34],1024);
    float* P_f2w  = add(d_in[35],262144);
    float* P_f2b  = add(d_in[36],256);

    bf16* m1w_bf = (bf16*)(base + 4185600);          // 10,616,832 B
    bf16* w2cl   = (bf16*)(base + 14802432);         // 36,864 B
    bf16* w3cl   = (bf16*)(base + 14839296);         // 147,456 B
    bf16* linv_bf= (bf16*)(base + 14986752);         // 524,288 B
    bf16* f1w_bf = (bf16*)(base + 15511040);         // 524,288 B
    bf16* f2w_bf = (bf16*)(base + 16035328);         // 524,288 B
    bf16* m2w_bf = (bf16*)(base + 16559616);         // 262,144 B
    char* pbase  = base + 16821760;
    float* p2d   = (float*)(pbase);                  // 16,384 B
    float* visf  = (float*)(pbase + 16384);          // 8,192 B
    float* evol  = (float*)(pbase + 24576);          // 524,288 B
    float* embp  = (float*)(pbase + 548864);         // 2,097,152 B
    float* obuf  = (float*)(pbase + 2646016);        // 2,097,152 B
    float* mlp1o = (float*)(pbase + 4743168);        // 4,194,304 B
    bf16*  mlp1o_bf = (bf16*)(pbase + 8937472);      // 2,097,152 B
    bf16*  fusedb_bf= (bf16*)(pbase + 11034624);     // 1,048,576 B
    char*  T     = pbase + 12083200;                 // transient, 21,233,664 B
    float* mv    = (float*)T;
    bf16*  volf_bf = (bf16*)(T + 786432);
    bf16*  c3act = (bf16*)T;
    bf16*  hbuf_bf = (bf16*)T;
    // total ≈ 50,138,624 B

    detect_kernel<<<1, 1, 0, stream>>>(d_in[3], flag);
    prep_kernel<<<dim3(64, NSEG+4), 256, 0, stream>>>(ca, pool, m1w, m1w_bf,
                                                      d_in[19], d_in[21], w2cl, w3cl,
                                                      d_in[11], d_in[33], d_in[35], d_in[25],
                                                      linv_bf, f1w_bf, f2w_bf, m2w_bf,
                                                      evol, 2228224, flag);

    proj_kernel<<<8, 256, 0, stream>>>(P_qc, P_camR, P_camC, P_camF, P_camP, p2d, visf, d_out, flag);
    cube_kernel<<<BKT, 128, 0, stream>>>(views, P_qc, qtime, P_camR, P_camC, P_camF, P_camP, P_csc, mv, flag);
    vol_conv3d_kernel<<<BKT, 128, 0, stream>>>(mv, P_v2vw, P_v2vb, volf_bf);
    gemm_bf16_kernel<0><<<dim3(4,8,8), 256, 0, stream>>>(volf_bf, linv_bf, nullptr, evol, nullptr, 512, 256, 1024, 2);
    for (int ch=0; ch<2; ++ch){
        int img0 = ch*IMG_CHUNK;
        patchconv_mfma_kernel<<<IMG_CHUNK, 256, 0, stream>>>(views, p2d, qtime, P_c1w, P_c1b,
                                                             w2cl, P_c2b, w3cl, P_c3b, c3act, img0, flag);
        gemm_bf16_kernel<0><<<dim3(8,16,9), 256, 0, stream>>>(c3act, m1w_bf, nullptr,
                                                             mlp1o + (size_t)img0*512, nullptr, IMG_CHUNK, 512, 10368, 18);
    }
    mlp1_fin_kernel<<<512, 256, 0, stream>>>(mlp1o, P_m1b, mlp1o_bf, 2048*512, 511);
    gemm_bf16_kernel<0><<<dim3(4,32,4), 256, 0, stream>>>(mlp1o_bf, m2w_bf, nullptr, embp, nullptr, 2048, 256, 512, 2);
    terms_kernel<<<2048, 256, 0, stream>>>(p2d, visf, evol, P_linvb, embp, P_m2b,
                                           P_linpw, P_linpb, P_lindw, P_lindb,
                                           P_tq, P_tt, P_vtab, P_gw, P_gb,
                                           qtime, ttime, P_qc, P_camC, P_csc, P_dns, fusedb_bf);
    gemm_bf16_kernel<1><<<dim3(16,32,1), 256, 0, stream>>>(fusedb_bf, f1w_bf, P_f1b, nullptr, hbuf_bf, 2048, 1024, 256, 4);
    gemm_bf16_kernel<0><<<dim3(4,32,4), 256, 0, stream>>>(hbuf_bf, f2w_bf, nullptr, obuf, nullptr, 2048, 256, 1024, 4);
    fin_out_kernel<<<512, 256, 0, stream>>>(obuf, P_f2b, d_out, flag, 2048*256, 255);
    (void)in_sizes; (void)n_in; (void)out_size; (void)ws_size;
}

// Round 11
// 500.088 us; speedup vs baseline: 1.2207x; 1.2207x over previous
//
#include <hip/hip_runtime.h>
#include <hip/hip_bf16.h>

typedef __hip_bfloat16 bf16;
typedef __attribute__((ext_vector_type(8))) short short8;
typedef __attribute__((ext_vector_type(4))) float floatx4;

#define NC 4
#define BB 2
#define TS 16
#define CHN 3
#define HH 256
#define WW 256
#define KQ 256
#define EE 256
#define BKT 512          // B*K
#define HW 65536         // H*W
#define IMG_CHUNK 1024   // images per patch-pipeline chunk (2 chunks of 2048)
#define NSEG 33
#define CH1 32
#define CH1P 40
#define CH2 64
#define CH2P 72
#define PW 11            // plane width (11 cols)

__device__ __forceinline__ float tof(bf16 x){ return __bfloat162float(x); }
__device__ __forceinline__ bf16 tobf(float x){ return __float2bfloat16(x); }
// exact GELU (erf form) — tanh approx exceeds absmax budget (R9 post-mortem)
__device__ __forceinline__ float gelu_f(float x){ return 0.5f*x*(1.f+erff(x*0.70710678118654752f)); }
__device__ __forceinline__ float ldx(const void* p, size_t i, int bf){
    return bf ? tof(((const bf16*)p)[i]) : ((const float*)p)[i];
}

struct CvtArgs { const void* src[NSEG]; int dstoff[NSEG]; int cnt[NSEG]; };

// ---------------------------------------------------------------- dtype detect
__global__ void detect_kernel(const void* camF, int* flag){
    unsigned short w0 = ((const unsigned short*)camF)[0];
    *flag = (w0 != 0) ? 1 : 0;
}

// ---------------------------------------------------------------- small tensors -> fp32 pool
__global__ __launch_bounds__(256) void convert_kernel(CvtArgs a, float* dst, const int* flag){
    int bf = *flag;
    int seg = blockIdx.y;
    const void* s = a.src[seg];
    float* d = dst + a.dstoff[seg];
    int n = a.cnt[seg];
    for (int i = blockIdx.x*blockDim.x + threadIdx.x; i < n; i += gridDim.x*blockDim.x)
        d[i] = bf ? tof(((const bf16*)s)[i]) : ((const float*)s)[i];
}

// ---------------------------------------------------------------- m1w -> bf16 (2048 blocks: full chip)
__global__ __launch_bounds__(256) void cvt_bf16_kernel(const void* src, bf16* dst, int n, const int* flagp){
    int bf = *flagp;
    int i = blockIdx.x*256 + threadIdx.x;
    int stride = gridDim.x*256;
    if (bf){
        const bf16* s = (const bf16*)src;
        for (; i<n; i+=stride) dst[i] = s[i];
    } else {
        const float* s = (const float*)src;
        for (; i<n; i+=stride) dst[i] = tobf(s[i]);
    }
}

// ---------------------------------------------------------------- conv2/3 weights raw -> channel-last bf16
__global__ __launch_bounds__(256) void cvt_wcl_kernel(const void* c2w_raw, const void* c3w_raw,
                                                      bf16* w2cl, bf16* w3cl, const int* flagp){
    int bf = *flagp;
    int i = blockIdx.x*256 + threadIdx.x;
    if (i < 64*32*9){
        int oc = i/(32*9), r = i%(32*9); int ic = r/9, tap = r%9;
        w2cl[tap*(64*CH1) + oc*CH1 + ic] = tobf(ldx(c2w_raw, i, bf));
    }
    if (i < 128*64*9){
        int oc = i/(64*9), r = i%(64*9); int ic = r/9, tap = r%9;
        w3cl[tap*(128*CH2) + oc*CH2 + ic] = tobf(ldx(c3w_raw, i, bf));
    }
}

// ---------------------------------------------------------------- aux weights raw -> bf16 (linv padded K=1024)
__global__ __launch_bounds__(256) void cvt_aux_kernel(
    const void* linv_raw, const void* f1w_raw, const void* f2w_raw, const void* m2w_raw,
    bf16* linv_bf, bf16* f1w_bf, bf16* f2w_bf, bf16* m2w_bf, const int* flagp)
{
    int bf = *flagp;
    int seg = blockIdx.y;
    int i0 = blockIdx.x*256 + threadIdx.x;
    int stride = gridDim.x*256;
    if (seg==0){
        for (int i=i0; i<256*1024; i+=stride){
            int r=i>>10, c=i&1023;
            linv_bf[i] = tobf(c<1000 ? ldx(linv_raw, (size_t)r*1000+c, bf) : 0.f);
        }
    } else if (seg==1){
        for (int i=i0; i<1024*256; i+=stride) f1w_bf[i]=tobf(ldx(f1w_raw,i,bf));
    } else if (seg==2){
        for (int i=i0; i<256*1024; i+=stride) f2w_bf[i]=tobf(ldx(f2w_raw,i,bf));
    } else {
        for (int i=i0; i<256*512; i+=stride) m2w_bf[i]=tobf(ldx(m2w_raw,i,bf));
    }
}

// ---------------------------------------------------------------- zero a float buffer
__global__ __launch_bounds__(256) void zero_kernel(float* p, int n){
    for (int i = blockIdx.x*256 + threadIdx.x; i < n; i += gridDim.x*256) p[i] = 0.f;
}

// ---------------------------------------------------------------- final output: obuf + bias -> d_out (dual dtype)
__global__ __launch_bounds__(256) void fin_out_kernel(const float* __restrict__ obuf,
                                                      const float* __restrict__ bias,
                                                      void* __restrict__ out, const int* __restrict__ flagp,
                                                      int total, int mask){
    int bf = *flagp;
    for (int i = blockIdx.x*256 + threadIdx.x; i < total; i += gridDim.x*256){
        float v = obuf[i] + bias[i & mask];
        if (bf) ((bf16*)out)[i] = tobf(v);
        else    ((float*)out)[i] = v;
    }
}

// ---------------------------------------------------------------- projection
__global__ __launch_bounds__(256) void proj_kernel(
    const float* __restrict__ qc, const float* __restrict__ camR,
    const float* __restrict__ camC, const float* __restrict__ camF,
    const float* __restrict__ camP,
    float* __restrict__ p2d, float* __restrict__ visf,
    void* __restrict__ dout, const int* __restrict__ flagp)
{
    int idx = blockIdx.x*256 + threadIdx.x;
    if (idx >= NC*BKT) return;
    int bf = *flagp;
    int c = idx / BKT, bk = idx % BKT;
    float dx = qc[bk*3+0] - camC[c*3+0];
    float dy = qc[bk*3+1] - camC[c*3+1];
    float dz = qc[bk*3+2] - camC[c*3+2];
    float X0 = camR[c*9+0]*dx + camR[c*9+1]*dy + camR[c*9+2]*dz;
    float X1 = camR[c*9+3]*dx + camR[c*9+4]*dy + camR[c*9+5]*dz;
    float X2 = camR[c*9+6]*dx + camR[c*9+7]*dy + camR[c*9+8]*dz;
    float z = fmaxf(X2, 1e-6f);
    float u = X0/z*camF[c*2+0] + camP[c*2+0];
    float v = X1/z*camF[c*2+1] + camP[c*2+1];
    p2d[idx*2+0] = u; p2d[idx*2+1] = v;
    bool vis = (X2 > 0.f) && (u >= 2.f) && (u <= (float)WW-2.f) && (v >= 2.f) && (v <= (float)HH-2.f);
    visf[idx] = vis ? 1.f : 0.f;
    float vv = vis ? 1.f : 0.f;
    size_t vidx = (size_t)BB*KQ*NC*EE + (size_t)bk*NC + c;
    if (bf) ((bf16*)dout)[vidx] = tobf(vv);
    else    ((float*)dout)[vidx] = vv;
}

// ---------------------------------------------------------------- cube sampling
__global__ __launch_bounds__(128) void cube_kernel(
    const void* __restrict__ views, const float* __restrict__ qc,
    const int* __restrict__ qtime,
    const float* __restrict__ camR, const float* __restrict__ camC,
    const float* __restrict__ camF, const float* __restrict__ camP,
    const float* __restrict__ csc, float* __restrict__ mv,
    const int* __restrict__ flagp)
{
    int bk = blockIdx.x; int p = threadIdx.x;
    if (p >= 125) return;
    int bf = *flagp;
    int b = bk / KQ;
    float cs2 = csc[0] * 2.f;
    int i = p/25, j = (p/5)%5, kz = p%5;
    float qx = qc[bk*3+0] + (float)(i-2)*cs2;
    float qy = qc[bk*3+1] + (float)(j-2)*cs2;
    float qz = qc[bk*3+2] + (float)(kz-2)*cs2;
    int t = qtime[bk];
    float a0=0.f,a1=0.f,a2=0.f,msum=0.f;
    for (int c=0;c<NC;++c){
        float dx=qx-camC[c*3+0], dy=qy-camC[c*3+1], dz=qz-camC[c*3+2];
        float X0 = camR[c*9+0]*dx+camR[c*9+1]*dy+camR[c*9+2]*dz;
        float X1 = camR[c*9+3]*dx+camR[c*9+4]*dy+camR[c*9+5]*dz;
        float X2 = camR[c*9+6]*dx+camR[c*9+7]*dy+camR[c*9+8]*dz;
        float z = fmaxf(X2,1e-6f);
        float u = X0/z*camF[c*2+0]+camP[c*2+0];
        float v = X1/z*camF[c*2+1]+camP[c*2+1];
        if (u>=0.f && u<=(float)WW && v>=0.f && v<=(float)HH){
            msum += 1.f;
            float x = u-0.5f, y = v-0.5f;
            float xf = floorf(x), yf = floorf(y);
            int ix=(int)xf, iy=(int)yf;
            float wx=x-xf, wy=y-yf;
            size_t base = (size_t)((c*BB+b)*TS + t)*CHN*HW;
            float wxs[2]={1.f-wx,wx}, wys[2]={1.f-wy,wy};
            #pragma unroll
            for (int ty=0;ty<2;++ty){
                int yy=iy+ty; if (yy<0||yy>=HH) continue;
                #pragma unroll
                for (int tx=0;tx<2;++tx){
                    int xx=ix+tx; if (xx<0||xx>=WW) continue;
                    float wt=wys[ty]*wxs[tx];
                    size_t o = base + (size_t)yy*WW+xx;
                    a0 += wt*ldx(views,o,bf);
                    a1 += wt*ldx(views,o+HW,bf);
                    a2 += wt*ldx(views,o+2*HW,bf);
                }
            }
        }
    }
    float cnt = fmaxf(msum,1.f);
    mv[(bk*125+p)*3+0]=a0/cnt;
    mv[(bk*125+p)*3+1]=a1/cnt;
    mv[(bk*125+p)*3+2]=a2/cnt;
}

// ---------------------------------------------------------------- 3D conv (v2v) + gelu -> bf16, padded K=1024 rows
__global__ __launch_bounds__(128) void vol_conv3d_kernel(
    const float* __restrict__ mv, const float* __restrict__ w,
    const float* __restrict__ bias, bf16* __restrict__ outb)
{
    int bk = blockIdx.x; int tid = threadIdx.x;
    __shared__ float vol[3][7][7][7];
    __shared__ float ws[648];
    __shared__ float bs[8];
    for (int idx=tid; idx<3*343; idx+=128) ((float*)vol)[idx]=0.f;
    for (int idx=tid; idx<648; idx+=128) ws[idx]=w[idx];
    if (tid<8) bs[tid]=bias[tid];
    __syncthreads();
    if (tid<125){
        int i=tid/25, j=(tid/5)%5, kz=tid%5;
        #pragma unroll
        for (int ch=0;ch<3;++ch) vol[ch][kz+1][j+1][i+1] = mv[(bk*125+tid)*3+ch];
    }
    __syncthreads();
    if (tid >= 104 && tid < 128) outb[bk*1024 + 1000 + (tid-104)] = tobf(0.f);
    if (tid<125){
        int w2=tid/25, h2=(tid/5)%5, d2=tid%5;
        for (int oc=0;oc<8;++oc){
            float acc = bs[oc];
            #pragma unroll
            for (int ic=0;ic<3;++ic)
              #pragma unroll
              for (int dz=0;dz<3;++dz)
                #pragma unroll
                for (int dy=0;dy<3;++dy)
                  #pragma unroll
                  for (int dxx=0;dxx<3;++dxx)
                    acc += vol[ic][d2+dz][h2+dy][w2+dxx] * ws[(((oc*3+ic)*3+dz)*3+dy)*3+dxx];
            outb[bk*1024 + oc*125 + tid] = tobf(gelu_f(acc));
        }
    }
}

// ---------------------------------------------------------------- fused patch sample + conv1 (VALU) + conv2/conv3 (MFMA)
// LDS: a2cl 17424 + a1cl 9680 + w1s 3456 + patch 1452 = 32,012 B -> 5 blocks/CU
__global__ __launch_bounds__(256) void patchconv_mfma_kernel(
    const void* __restrict__ views, const float* __restrict__ p2d,
    const int* __restrict__ qtime,
    const float* __restrict__ w1, const float* __restrict__ b1,
    const bf16* __restrict__ w2cl, const float* __restrict__ b2,
    const bf16* __restrict__ w3cl, const float* __restrict__ b3,
    bf16* __restrict__ act_out, int img0, const int* __restrict__ flagp)
{
    int img = img0 + blockIdx.x;
    int c = img>>9, b = (img>>8)&1, k = img&255;
    int bk = b*KQ + k;
    int tid = threadIdx.x;
    int wave = tid>>6, lane = tid&63;

    __shared__ __align__(16) bf16 a2cl[11*PW*CH2P];   // 17,424 B
    __shared__ __align__(16) bf16 a1cl[11*PW*CH1P];   // 9,680 B
    __shared__ float w1s[864];                        // 3,456 B
    __shared__ float patch[3][11][11];                // 1,452 B

    for (int i=tid;i<3*11*11;i+=256) ((float*)patch)[i]=0.f;
    for (int i=tid;i<864;i+=256) w1s[i]=w1[i];
    {
        unsigned int* z1=(unsigned int*)a1cl; int n1 = 11*PW*CH1P/2;
        for (int i=tid;i<n1;i+=256) z1[i]=0u;
        unsigned int* z2=(unsigned int*)a2cl; int n2 = 11*PW*CH2P/2;
        for (int i=tid;i<n2;i+=256) z2[i]=0u;
    }
    __syncthreads();
    if (tid<81){
        int bf = *flagp;
        float u=p2d[(c*BKT+bk)*2+0], v=p2d[(c*BKT+bk)*2+1];
        int t=qtime[bk];
        int r=tid/9,q=tid%9;
        float x=u+(float)(q-4), y=v+(float)(r-4);
        float xf=floorf(x), yf=floorf(y);
        int ix=(int)xf, iy=(int)yf;
        float wx=x-xf, wy=y-yf;
        size_t base = (size_t)((c*BB+b)*TS+t)*CHN*HW;
        float v0=0.f,v1=0.f,v2=0.f;
        float wxs[2]={1.f-wx,wx}, wys[2]={1.f-wy,wy};
        #pragma unroll
        for (int ty=0;ty<2;++ty){
            int yy=iy+ty; if (yy<0||yy>=HH) continue;
            #pragma unroll
            for (int tx=0;tx<2;++tx){
                int xx=ix+tx; if (xx<0||xx>=WW) continue;
                float wt=wys[ty]*wxs[tx];
                size_t o = base + (size_t)yy*WW+xx;
                v0 += wt*ldx(views,o,bf);
                v1 += wt*ldx(views,o+HW,bf);
                v2 += wt*ldx(views,o+2*HW,bf);
            }
        }
        patch[0][r+1][q+1]=v0; patch[1][r+1][q+1]=v1; patch[2][r+1][q+1]=v2;
    }
    __syncthreads();
    for (int o=tid;o<81*32;o+=256){
        int oc=o&31, pp=o>>5;
        int r=pp/9, q=pp-9*r;
        float acc=b1[oc];
        #pragma unroll
        for (int ic=0;ic<3;++ic)
          #pragma unroll
          for (int dy2=0;dy2<3;++dy2)
            #pragma unroll
            for (int dx2=0;dx2<3;++dx2)
              acc += patch[ic][r+dy2][q+dx2]*w1s[((oc*3+ic)*3+dy2)*3+dx2];
        a1cl[((r+1)*PW+(q+1))*CH1P + oc] = tobf(gelu_f(acc));
    }
    __syncthreads();
    int mrow = lane&15;
    int kgrp = lane>>4;
    int koff = kgrp<<3;
    {
        int baseoff[6];
        #pragma unroll
        for (int m=0;m<6;++m){
            int pos = m*16 + mrow; if (pos>80) pos=80;
            int r=pos/9, q=pos-9*r;
            baseoff[m] = (r*PW+q)*CH1P + koff;
        }
        floatx4 acc2[6];
        #pragma unroll
        for (int m=0;m<6;++m) acc2[m]=(floatx4){0.f,0.f,0.f,0.f};
        int n0 = wave<<4;
        #pragma unroll
        for (int tap=0; tap<9; ++tap){
            int dy=tap/3, dx=tap-3*dy;
            short8 bfrag = *(const short8*)(w2cl + ((size_t)tap*64 + n0 + mrow)*CH1 + koff);
            int toff = (dy*PW+dx)*CH1P;
            #pragma unroll
            for (int m=0;m<6;++m){
                short8 afrag = *(const short8*)&a1cl[baseoff[m]+toff];
                acc2[m] = __builtin_amdgcn_mfma_f32_16x16x32_bf16(afrag, bfrag, acc2[m], 0,0,0);
            }
        }
        int oc = n0 + mrow;
        float bb = b2[oc];
        #pragma unroll
        for (int m=0;m<6;++m){
            #pragma unroll
            for (int rg=0;rg<4;++rg){
                int pos = m*16 + (kgrp<<2)+rg;
                if (pos<=80){
                    int r=pos/9,q=pos-9*r;
                    a2cl[((r+1)*PW+(q+1))*CH2P + oc] = tobf(gelu_f(acc2[m][rg]+bb));
                }
            }
        }
    }
    __syncthreads();
    {
        int baseoff[6];
        #pragma unroll
        for (int m=0;m<6;++m){
            int pos = m*16 + mrow; if (pos>80) pos=80;
            int r=pos/9, q=pos-9*r;
            baseoff[m] = (r*PW+q)*CH2P;
        }
        floatx4 acc3[2][6];
        #pragma unroll
        for (int nt=0;nt<2;++nt)
          #pragma unroll
          for (int m=0;m<6;++m) acc3[nt][m]=(floatx4){0.f,0.f,0.f,0.f};
        int n0 = wave<<5;
        #pragma unroll
        for (int tap=0; tap<9; ++tap){
            int dy=tap/3, dx=tap-3*dy;
            int toff = (dy*PW+dx)*CH2P;
            #pragma unroll
            for (int ks=0;ks<2;++ks){
                int kof2 = (ks<<5) + koff;
                short8 b0 = *(const short8*)(w3cl + ((size_t)tap*128 + n0      + mrow)*CH2 + kof2);
                short8 b1f= *(const short8*)(w3cl + ((size_t)tap*128 + n0 + 16 + mrow)*CH2 + kof2);
                #pragma unroll
                for (int m=0;m<6;++m){
                    short8 af = *(const short8*)&a2cl[baseoff[m]+toff+kof2];
                    acc3[0][m] = __builtin_amdgcn_mfma_f32_16x16x32_bf16(af, b0,  acc3[0][m], 0,0,0);
                    acc3[1][m] = __builtin_amdgcn_mfma_f32_16x16x32_bf16(af, b1f, acc3[1][m], 0,0,0);
                }
            }
        }
        #pragma unroll
        for (int nt=0;nt<2;++nt){
            int oc = n0 + (nt<<4) + mrow;
            float bb = b3[oc];
            #pragma unroll
            for (int m=0;m<6;++m){
                #pragma unroll
                for (int rg=0;rg<4;++rg){
                    int pos = m*16 + (kgrp<<2)+rg;
                    if (pos<=80)
                        act_out[(size_t)blockIdx.x*10368 + oc*81 + pos] = tobf(gelu_f(acc3[nt][m][rg]+bb));
                }
            }
        }
    }
}

// ---------------------------------------------------------------- generic MFMA bf16 GEMM, double-buffered LDS + reg prefetch
template<int OUT>
__global__ __launch_bounds__(256) void gemm_bf16_kernel(
    const bf16* __restrict__ A, const bf16* __restrict__ W, const float* __restrict__ bias,
    float* __restrict__ Cf, bf16* __restrict__ Cb, int M, int N, int K, int iters)
{
    __shared__ bf16 As[2][64][72];
    __shared__ bf16 Bs[2][64][72];
    int tid = threadIdx.x;
    int wave = tid>>6, lane = tid&63;
    int m0 = blockIdx.y<<6, n0 = blockIdx.x<<6;
    int kt0 = blockIdx.z*iters;
    int lr = tid>>3;
    int lc = (tid&7)<<3;
    const bf16* Ap0 = A + (size_t)(m0+lr)*K    + (kt0<<6) + lc;
    const bf16* Ap1 = A + (size_t)(m0+lr+32)*K + (kt0<<6) + lc;
    const bf16* Wp0 = W + (size_t)(n0+lr)*K    + (kt0<<6) + lc;
    const bf16* Wp1 = W + (size_t)(n0+lr+32)*K + (kt0<<6) + lc;
    uint4 ra0 = *(const uint4*)Ap0;
    uint4 ra1 = *(const uint4*)Ap1;
    uint4 rb0 = *(const uint4*)Wp0;
    uint4 rb1 = *(const uint4*)Wp1;
    floatx4 acc[4];
    #pragma unroll
    for (int j=0;j<4;++j) acc[j] = (floatx4){0.f,0.f,0.f,0.f};
    int arow = (wave<<4) + (lane&15);
    int koff = (lane>>4)<<3;
    int nrow = lane&15;
    *(uint4*)&As[0][lr][lc]    = ra0;
    *(uint4*)&As[0][lr+32][lc] = ra1;
    *(uint4*)&Bs[0][lr][lc]    = rb0;
    *(uint4*)&Bs[0][lr+32][lc] = rb1;
    __syncthreads();
    for (int it=0; it<iters; ++it){
        int cur = it&1;
        if (it+1<iters){
            int off = (it+1)<<6;
            ra0 = *(const uint4*)(Ap0+off);
            ra1 = *(const uint4*)(Ap1+off);
            rb0 = *(const uint4*)(Wp0+off);
            rb1 = *(const uint4*)(Wp1+off);
        }
        #pragma unroll
        for (int kk=0; kk<64; kk+=32){
            short8 af = *(const short8*)&As[cur][arow][kk+koff];
            #pragma unroll
            for (int j=0;j<4;++j){
                short8 bfr = *(const short8*)&Bs[cur][(j<<4)+nrow][kk+koff];
                acc[j] = __builtin_amdgcn_mfma_f32_16x16x32_bf16(af, bfr, acc[j], 0, 0, 0);
            }
        }
        if (it+1<iters){
            __syncthreads();
            int nxt = cur^1;
            *(uint4*)&As[nxt][lr][lc]    = ra0;
            *(uint4*)&As[nxt][lr+32][lc] = ra1;
            *(uint4*)&Bs[nxt][lr][lc]    = rb0;
            *(uint4*)&Bs[nxt][lr+32][lc] = rb1;
            __syncthreads();
        }
    }
    int crow = (wave<<4) + ((lane>>4)<<2);
    int ccol = lane&15;
    #pragma unroll
    for (int j=0;j<4;++j){
        int n = n0 + (j<<4) + ccol;
        if (OUT==0){
            #pragma unroll
            for (int r=0;r<4;++r)
                atomicAdd(&Cf[(size_t)(m0+crow+r)*N + n], acc[j][r]);
        } else {
            float bb = bias[n];
            #pragma unroll
            for (int r=0;r<4;++r)
                Cb[(size_t)(m0+crow+r)*N + n] = tobf(gelu_f(acc[j][r] + bb));
        }
    }
}

// ---------------------------------------------------------------- mlp1 finalize: bf16 out = gelu(acc + bias)
__global__ __launch_bounds__(256) void mlp1_fin_kernel(const float* __restrict__ C,
                                                       const float* __restrict__ bias,
                                                       bf16* __restrict__ Cb, int total, int Nmask){
    for (int i = blockIdx.x*256 + threadIdx.x; i < total; i += gridDim.x*256)
        Cb[i] = tobf(gelu_f(C[i] + bias[i & Nmask]));
}

// ---------------------------------------------------------------- terms + gates + fuse -> bf16 (evol/embp bias folded in)
__global__ __launch_bounds__(256) void terms_kernel(
    const float* __restrict__ p2d, const float* __restrict__ visf,
    const float* __restrict__ evol, const float* __restrict__ linv_b,
    const float* __restrict__ embp, const float* __restrict__ m2_b,
    const float* __restrict__ lin_pos_w, const float* __restrict__ lin_pos_b,
    const float* __restrict__ lin_depth_w, const float* __restrict__ lin_depth_b,
    const float* __restrict__ tq_emb, const float* __restrict__ tt_emb,
    const float* __restrict__ vis_tab,
    const float* __restrict__ gate_w, const float* __restrict__ gate_b,
    const int* __restrict__ qtime, const int* __restrict__ ttime,
    const float* __restrict__ qc, const float* __restrict__ camC,
    const float* __restrict__ csc, const float* __restrict__ dns,
    bf16* __restrict__ fused)
{
    int row = blockIdx.x;
    int c = row & 3; int bk = row >> 2;
    int tid = threadIdx.x;
    __shared__ float feats[40];
    __shared__ float dfeat[20];
    __shared__ float terms[7][256];
    __shared__ float wred[4][7];
    __shared__ float gates_s[7];
    float u = p2d[(c*BKT+bk)*2+0], v = p2d[(c*BKT+bk)*2+1];
    if (tid < 40){
        int j = tid/20; int rem = tid%20;
        float xval = (j==0) ? u*(1.f/(float)WW) : v*(1.f/(float)HH);
        int fi = rem % 10; bool iscos = (rem >= 10);
        float arg = xval * (float)(1<<fi) * 3.14159265358979323846f;
        feats[tid] = iscos ? cosf(arg) : sinf(arg);
    } else if (tid < 60){
        int rem = tid-40;
        float dx = qc[bk*3+0]-camC[c*3+0];
        float dy = qc[bk*3+1]-camC[c*3+1];
        float dz = qc[bk*3+2]-camC[c*3+2];
        float dep = sqrtf(dx*dx+dy*dy+dz*dz) / (csc[0] * dns[0]);
        int fi = rem % 10; bool iscos = (rem >= 10);
        float arg = dep * (float)(1<<fi) * 3.14159265358979323846f;
        dfeat[rem] = iscos ? cosf(arg) : sinf(arg);
    }
    __syncthreads();
    int e = tid;
    float pos = lin_pos_b[e];
    for (int j2=0;j2<40;++j2) pos += feats[j2]*lin_pos_w[e*40+j2];
    float dep = lin_depth_b[e];
    for (int j2=0;j2<20;++j2) dep += dfeat[j2]*lin_depth_w[e*20+j2];
    float vol = evol[bk*256+e] + linv_b[e];
    int img = (c*BB + (bk>>8))*KQ + (bk&255);
    float pat = embp[(size_t)img*256+e] + m2_b[e];
    int tq = qtime[bk], tt2 = ttime[bk];
    float qtv = tq_emb[tq*256+e];
    float ttv = tt_emb[tt2*256+e];
    int vb = (visf[c*BKT+bk] > 0.5f) ? 1 : 0;
    float viv = vis_tab[vb*256+e];
    terms[0][e]=pos; terms[1][e]=vol; terms[2][e]=pat; terms[3][e]=qtv;
    terms[4][e]=ttv; terms[5][e]=viv; terms[6][e]=dep;
    __syncthreads();
    float pg[7];
    #pragma unroll
    for (int g=0;g<7;++g) pg[g]=0.f;
    for (int j2=tid; j2<1792; j2+=256){
        float cv = ((const float*)terms)[j2];
        #pragma unroll
        for (int g=0;g<7;++g) pg[g] += cv * gate_w[g*1792 + j2];
    }
    #pragma unroll
    for (int g=0;g<7;++g){
        #pragma unroll
        for (int off=32; off>0; off>>=1) pg[g] += __shfl_down(pg[g], off, 64);
    }
    int wave = tid >> 6, lane = tid & 63;
    if (lane==0){
        #pragma unroll
        for (int g=0;g<7;++g) wred[wave][g]=pg[g];
    }
    __syncthreads();
    if (tid < 7){
        float s = wred[0][tid]+wred[1][tid]+wred[2][tid]+wred[3][tid] + gate_b[tid];
        gates_s[tid] = 1.f/(1.f+expf(-s));
    }
    __syncthreads();
    float fv = 0.f;
    #pragma unroll
    for (int g=0;g<7;++g) fv += gates_s[g]*terms[g][e];
    fused[(size_t)row*256 + e] = tobf(fv);
}

// ---------------------------------------------------------------- launch
extern "C" void kernel_launch(void* const* d_in, const int* in_sizes, int n_in,
                              void* d_out, int out_size, void* d_ws, size_t ws_size,
                              hipStream_t stream) {
    const void* views  = d_in[0];
    const int*  qtime  = (const int*)d_in[6];
    const int*  ttime  = (const int*)d_in[7];
    const void* m1w    = d_in[23];

    char* base = (char*)d_ws;
    int*   flag = (int*)base;                       // 256 B
    float* pool = (float*)(base + 256);

    CvtArgs ca; int poff = 0; int ns = 0;
    auto add = [&](const void* p, int n)->float* {
        ca.src[ns]=p; ca.dstoff[ns]=poff; ca.cnt[ns]=n;
        float* r = pool+poff; poff += n; ns++; return r;
    };
    float* P_camR = add(d_in[1],36);
    float* P_camC = add(d_in[2],12);
    float* P_camF = add(d_in[3],8);
    float* P_camP = add(d_in[4],8);
    float* P_qc   = add(d_in[5],1536);
    float* P_csc  = add(d_in[8],1);
    float* P_dns  = add(d_in[30],1);
    float* P_v2vw = add(d_in[9],648);
    float* P_v2vb = add(d_in[10],8);
    float* P_linvw= add(d_in[11],256000);
    float* P_linvb= add(d_in[12],256);
    float* P_linpw= add(d_in[13],10240);
    float* P_linpb= add(d_in[14],256);
    float* P_lindw= add(d_in[15],5120);
    float* P_lindb= add(d_in[16],256);
    float* P_c1w  = add(d_in[17],864);
    float* P_c1b  = add(d_in[18],32);
    float* P_c2w  = add(d_in[19],18432);
    float* P_c2b  = add(d_in[20],64);
    float* P_c3w  = add(d_in[21],73728);
    float* P_c3b  = add(d_in[22],128);
    float* P_m1b  = add(d_in[24],512);
    float* P_m2w  = add(d_in[25],131072);
    float* P_m2b  = add(d_in[26],256);
    float* P_tq   = add(d_in[27],4096);
    float* P_tt   = add(d_in[28],4096);
    float* P_vtab = add(d_in[29],512);
    float* P_gw   = add(d_in[31],12544);
    float* P_gb   = add(d_in[32],7);
    float* P_f1w  = add(d_in[33],262144);
    float* P_f1b  = add(d_in[34],1024);
    float* P_f2w  = add(d_in[35],262144);
    float* P_f2b  = add(d_in[36],256);

    bf16* m1w_bf = (bf16*)(base + 4185600);          // 10,616,832 B
    bf16* w2cl   = (bf16*)(base + 14802432);         // 36,864 B
    bf16* w3cl   = (bf16*)(base + 14839296);         // 147,456 B
    bf16* linv_bf= (bf16*)(base + 14986752);         // 524,288 B
    bf16* f1w_bf = (bf16*)(base + 15511040);         // 524,288 B
    bf16* f2w_bf = (bf16*)(base + 16035328);         // 524,288 B
    bf16* m2w_bf = (bf16*)(base + 16559616);         // 262,144 B
    char* pbase  = base + 16821760;
    float* p2d   = (float*)(pbase);                  // 16,384 B
    float* visf  = (float*)(pbase + 16384);          // 8,192 B
    float* evol  = (float*)(pbase + 24576);          // 524,288 B
    float* embp  = (float*)(pbase + 548864);         // 2,097,152 B
    float* obuf  = (float*)(pbase + 2646016);        // 2,097,152 B
    float* mlp1o = (float*)(pbase + 4743168);        // 4,194,304 B
    bf16*  mlp1o_bf = (bf16*)(pbase + 8937472);      // 2,097,152 B
    bf16*  fusedb_bf= (bf16*)(pbase + 11034624);     // 1,048,576 B
    char*  T     = pbase + 12083200;                 // transient, 21,233,664 B
    float* mv    = (float*)T;
    bf16*  volf_bf = (bf16*)(T + 786432);
    bf16*  c3act = (bf16*)T;
    bf16*  hbuf_bf = (bf16*)T;
    // total ≈ 50,138,624 B

    detect_kernel<<<1, 1, 0, stream>>>(d_in[3], flag);
    convert_kernel<<<dim3(64, NSEG), 256, 0, stream>>>(ca, pool, flag);
    cvt_bf16_kernel<<<2048, 256, 0, stream>>>(m1w, m1w_bf, 512*10368, flag);
    cvt_wcl_kernel<<<288, 256, 0, stream>>>(d_in[19], d_in[21], w2cl, w3cl, flag);
    cvt_aux_kernel<<<dim3(256,4), 256, 0, stream>>>(d_in[11], d_in[33], d_in[35], d_in[25],
                                                    linv_bf, f1w_bf, f2w_bf, m2w_bf, flag);
    zero_kernel<<<2048, 256, 0, stream>>>(evol, 2228224);

    proj_kernel<<<8, 256, 0, stream>>>(P_qc, P_camR, P_camC, P_camF, P_camP, p2d, visf, d_out, flag);
    cube_kernel<<<BKT, 128, 0, stream>>>(views, P_qc, qtime, P_camR, P_camC, P_camF, P_camP, P_csc, mv, flag);
    vol_conv3d_kernel<<<BKT, 128, 0, stream>>>(mv, P_v2vw, P_v2vb, volf_bf);
    gemm_bf16_kernel<0><<<dim3(4,8,8), 256, 0, stream>>>(volf_bf, linv_bf, nullptr, evol, nullptr, 512, 256, 1024, 2);
    for (int ch=0; ch<2; ++ch){
        int img0 = ch*IMG_CHUNK;
        patchconv_mfma_kernel<<<IMG_CHUNK, 256, 0, stream>>>(views, p2d, qtime, P_c1w, P_c1b,
                                                             w2cl, P_c2b, w3cl, P_c3b, c3act, img0, flag);
        gemm_bf16_kernel<0><<<dim3(8,16,9), 256, 0, stream>>>(c3act, m1w_bf, nullptr,
                                                             mlp1o + (size_t)img0*512, nullptr, IMG_CHUNK, 512, 10368, 18);
    }
    mlp1_fin_kernel<<<512, 256, 0, stream>>>(mlp1o, P_m1b, mlp1o_bf, 2048*512, 511);
    gemm_bf16_kernel<0><<<dim3(4,32,4), 256, 0, stream>>>(mlp1o_bf, m2w_bf, nullptr, embp, nullptr, 2048, 256, 512, 2);
    terms_kernel<<<2048, 256, 0, stream>>>(p2d, visf, evol, P_linvb, embp, P_m2b,
                                           P_linpw, P_linpb, P_lindw, P_lindb,
                                           P_tq, P_tt, P_vtab, P_gw, P_gb,
                                           qtime, ttime, P_qc, P_camC, P_csc, P_dns, fusedb_bf);
    gemm_bf16_kernel<1><<<dim3(16,32,1), 256, 0, stream>>>(fusedb_bf, f1w_bf, P_f1b, nullptr, hbuf_bf, 2048, 1024, 256, 4);
    gemm_bf16_kernel<0><<<dim3(4,32,4), 256, 0, stream>>>(hbuf_bf, f2w_bf, nullptr, obuf, nullptr, 2048, 256, 1024, 4);
    fin_out_kernel<<<512, 256, 0, stream>>>(obuf, P_f2b, d_out, flag, 2048*256, 255);
    (void)in_sizes; (void)n_in; (void)out_size; (void)ws_size;
}